// Round 7
// baseline (597.643 us; speedup 1.0000x reference)
//
#include <hip/hip_runtime.h>
#include <cmath>

typedef __attribute__((ext_vector_type(8))) _Float16 half8;
typedef __attribute__((ext_vector_type(8))) unsigned short ushort8;
typedef __attribute__((ext_vector_type(4))) float f32x4;

#define HH 7168
#define NE 256
#define NQ 224        // K32 chunks
#define NITER 224     // 32-K barrier iterations
#define NWIN 112      // 64-K A-windows
#define TOPK 8
#define TOPKG 4
#define WSC 1024.f
#define INV_WS (1.f/1024.f)
#define C1 (1.f/2048.f)       // 2^-11
#define C2 (1.f/4194304.f)    // 2^-22

// 2-level f16 split: x = h + m*2^-11, residual ~2^-25|x|
__device__ __forceinline__ void split2(float x, unsigned short& h, unsigned short& m){
  const _Float16 hh = (_Float16)x;
  const float r = x - (float)hh;                 // exact
  const _Float16 mm = (_Float16)(r * 2048.f);
  h = __builtin_bit_cast(unsigned short, hh);
  m = __builtin_bit_cast(unsigned short, mm);
}

// W*1024 -> (h,m) f16 in MFMA B-fragment order, coalesced writes.
// slot(q,nt,L) holds B[k=32q+8(L>>4)+j][e=16nt+(L&15)], j=0..7.
__global__ __launch_bounds__(256) void prep_w(const float* __restrict__ wgt,
                                              unsigned short* __restrict__ bh,
                                              unsigned short* __restrict__ bm){
  const int b = blockIdx.x;                 // 896 = 16 nt * 56 q-groups
  const int nt = b & 15, qb = (b >> 4) * 4;
  const int w = threadIdx.x >> 6, L = threadIdx.x & 63;
  const int q = qb + w;
  const int e = nt*16 + (L & 15);
  const int k0 = 32*q + 8*(L >> 4);
  const float4 a0 = *(const float4*)(wgt + (size_t)e*HH + k0);
  const float4 a1 = *(const float4*)(wgt + (size_t)e*HH + k0 + 4);
  const float v[8] = {a0.x,a0.y,a0.z,a0.w,a1.x,a1.y,a1.z,a1.w};
  ushort8 h8, m8;
#pragma unroll
  for(int j=0;j<8;j++){ unsigned short hh,mm; split2(v[j]*WSC, hh, mm); h8[j]=hh; m8[j]=mm; }
  const size_t base = ((size_t)(q*16+nt)*64 + L)*8;
  *(ushort8*)(bh+base) = h8;
  *(ushort8*)(bm+base) = m8;
}

// ---------------- GEMM: square 32x32 wave tiles AT 2 blocks/CU ----------------
// Block = 64 tok x 128 exp, 512 thr / 8 waves (2mtp x 4ntp), wave = 32tok x 32exp.
// Regime law (R1/R4/R6): need >=4 waves/SIMD -> LDS must be <=80 KB.
// Fix vs R6: barrier-step BK=32 (B dbuf 2x16 KB) + A staged per 64-K window
// (A dbuf 2x16 KB, exact R6 mapping/swizzle, proven 0-conflict) = 64 KB total.
// DS: 8 ds_read_b128 per 16 MFMA (0.5/MFMA vs R2's 0.75); split2 once/element.
// Schedule = proven R2 simple loop: glds B depth-1, ga at even iters, stage at
// odd iters, full-drain __syncthreads. MFMA order + Kahan 128-K flush points
// element-identical to R2/R6 -> bit-identical logits, absmax 0.
#define AB(aw,lvl,mt,q,row) ((((((aw)*2+(lvl))*4+(mt))*2+(q))*64+(row))*16)
#define BB32(lvl,nt) (((lvl)*8+(nt))<<10)
__device__ __forceinline__ int swz(int bo){ return bo ^ (((bo >> 8) & 7) << 4); }

__device__ __forceinline__ void glds16(const void* g, void* l){
  __builtin_amdgcn_global_load_lds(
      (const __attribute__((address_space(1))) unsigned int*)g,
      (__attribute__((address_space(3))) unsigned int*)l, 16, 0, 0);
}

__global__ __launch_bounds__(512,4)
void gemm(const float* __restrict__ hs,
          const unsigned short* __restrict__ bhp,
          const unsigned short* __restrict__ bmp,
          float* __restrict__ lgout){
  __shared__ __align__(16) unsigned char blds[32768];  // 2buf x (2lvl x 8nt x 1KB)
  __shared__ __align__(16) unsigned char alds[32768];  // 2buf x 2lvl x 4mt x 2qh x 64row x 16B

  const int tid = threadIdx.x, lane = tid & 63, w = tid >> 6;
  const int b = blockIdx.x;                // 256 blocks -> 2 blocks/CU
  const int slice = (b >> 2) & 1;          // XCD 0-3 -> slice0, 4-7 -> slice1 (L2-resident)
  const int tg = (b >> 3)*4 + (b & 3);     // 0..127
  const int tb = tg*64, eb = slice*128;
  const int mtp = w >> 2, ntp = w & 3;     // wave tile: mt {2mtp,2mtp+1} x ntl {2ntp,2ntp+1}

  f32x4 ksum[2][2], kcmp[2][2], c0[2][2], c1[2][2], c2[2][2];
#pragma unroll
  for(int a=0;a<2;a++)
#pragma unroll
    for(int c=0;c<2;c++){ ksum[a][c]=f32x4{0,0,0,0}; kcmp[a][c]=f32x4{0,0,0,0}; }

  // A staging (R6 mapping): thread -> token tid>>3, 8 consecutive k at (tid&7)*8
  const int tokS = tid >> 3, kidx = tid & 7;
  const int mtS = tokS >> 4, m16S = tokS & 15;
  const int qS = kidx >> 2, kgS = kidx & 3;        // qh half, k-octet
  const int rowS = kgS*16 + m16S;
  const float* agp = hs + (size_t)(tb + tokS)*HH + kidx*8;
  float4 ga[2];

  auto stage = [&](int aw){
    unsigned short h[8], m[8];
    const float* gv = (const float*)ga;
#pragma unroll
    for(int p=0;p<8;p++) split2(gv[p], h[p], m[p]);
    ushort8 h8, m8;
#pragma unroll
    for(int j=0;j<8;j++){ h8[j]=h[j]; m8[j]=m[j]; }
    *(ushort8*)&alds[swz(AB(aw,0,mtS,qS,rowS))] = h8;
    *(ushort8*)&alds[swz(AB(aw,1,mtS,qS,rowS))] = m8;
  };

  // B staging: 16 slots (2lvl x 8nt) of 1KB per buf, 2 glds16 per wave per iter
  auto bstage = [&](int bufoff, int q32){
#pragma unroll
    for(int j=0;j<2;j++){
      const int sid = w*2 + j;
      const int lvl = sid >> 3, nt = sid & 7;
      const unsigned short* src = (lvl ? bmp : bhp)
          + ((size_t)((q32*16 + slice*8 + nt)*64 + lane))*8;
      glds16(src, &blds[bufoff + BB32(lvl,nt)]);
    }
  };

  auto compute = [&](int aw, int qh, int bbuf){
    half8 ah[2], am[2];
#pragma unroll
    for(int mtl=0;mtl<2;mtl++){
      const int mt = mtp*2 + mtl;
      ah[mtl] = *(const half8*)&alds[swz(AB(aw,0,mt,qh,lane))];
      am[mtl] = *(const half8*)&alds[swz(AB(aw,1,mt,qh,lane))];
    }
    half8 Bh[2], Bm[2];
#pragma unroll
    for(int ntl=0;ntl<2;ntl++){
      Bh[ntl] = *(const half8*)&blds[bbuf + BB32(0,ntp*2+ntl) + lane*16];
      Bm[ntl] = *(const half8*)&blds[bbuf + BB32(1,ntp*2+ntl) + lane*16];
    }
    __builtin_amdgcn_s_setprio(1);
#pragma unroll
    for(int mtl=0;mtl<2;mtl++)
#pragma unroll
      for(int ntl=0;ntl<2;ntl++){
        c0[mtl][ntl] = __builtin_amdgcn_mfma_f32_16x16x32_f16(ah[mtl], Bh[ntl], c0[mtl][ntl], 0,0,0);
        c1[mtl][ntl] = __builtin_amdgcn_mfma_f32_16x16x32_f16(ah[mtl], Bm[ntl], c1[mtl][ntl], 0,0,0);
        c1[mtl][ntl] = __builtin_amdgcn_mfma_f32_16x16x32_f16(am[mtl], Bh[ntl], c1[mtl][ntl], 0,0,0);
        c2[mtl][ntl] = __builtin_amdgcn_mfma_f32_16x16x32_f16(am[mtl], Bm[ntl], c2[mtl][ntl], 0,0,0);
      }
    __builtin_amdgcn_s_setprio(0);
  };

  // ---- prologue: A window 0 + B chunk 0 into buf 0
  ga[0] = *(const float4*)agp;
  ga[1] = *(const float4*)(agp + 4);
  bstage(0, 0);
  stage(0);
  __syncthreads();

#pragma unroll 1
  for(int i=0;i<NITER;i++){
    const int wnd = i >> 1, qh = i & 1;
    const int aw = wnd & 1;                // A read buf
    const int bcur = (i & 1) ? 16384 : 0;  // B read buf
    const bool moreB = (i+1 < NITER);
    const bool moreA = (wnd+1 < NWIN);

    if(moreB) bstage(bcur ^ 16384, i+1);   // B chunk i+1, depth-1
    if(qh == 0 && moreA){                   // ga for window wnd+1 (staged next iter)
      const float* ap = agp + (size_t)(wnd+1)*64;
      ga[0] = *(const float4*)ap;
      ga[1] = *(const float4*)(ap + 4);
    }
    if((i & 3) == 0){
#pragma unroll
      for(int a=0;a<2;a++)
#pragma unroll
        for(int c=0;c<2;c++){ c0[a][c]=f32x4{0,0,0,0}; c1[a][c]=f32x4{0,0,0,0}; c2[a][c]=f32x4{0,0,0,0}; }
    }
    compute(aw, qh, bcur);
    if(qh == 1 && moreA) stage(aw ^ 1);    // window wnd+1 into opposite buf
    if((i & 3) == 3){
      // Kahan flush of the completed 128-K window (same points as R2/R6 -> bit-identical)
#pragma unroll
      for(int a=0;a<2;a++)
#pragma unroll
        for(int c=0;c<2;c++)
#pragma unroll
          for(int r=0;r<4;r++){
            const float v = c0[a][c][r] + c1[a][c][r]*C1 + c2[a][c][r]*C2;
            const float y = v - kcmp[a][c][r];
            const float t = ksum[a][c][r] + y;
            kcmp[a][c][r] = (t - ksum[a][c][r]) - y;
            ksum[a][c][r] = t;
          }
    }
    __syncthreads();
  }

  // epilogue: C layout col=lane&15 (expert), row=(lane>>4)*4+r (token); undo W scale
#pragma unroll
  for(int mtl=0;mtl<2;mtl++)
#pragma unroll
    for(int ntl=0;ntl<2;ntl++)
#pragma unroll
      for(int r=0;r<4;r++){
        const int tok = (mtp*2+mtl)*16 + (lane>>4)*4 + r;
        const int e = (ntp*2+ntl)*16 + (lane&15);
        const float lg = (ksum[mtl][ntl][r] - kcmp[mtl][ntl][r]) * INV_WS;
        lgout[(size_t)(tb+tok)*NE + eb + e] = lg;
      }
}

// Gating, 1 token per wave, grid T/4.
__global__ __launch_bounds__(256)
void gate(const float* __restrict__ lg, const float* __restrict__ bias,
          float* __restrict__ out, int T){
  const int tid = threadIdx.x, lane = tid & 63, wv = tid >> 6;
  const int t = blockIdx.x*4 + wv;
  const float4 bias4 = *(const float4*)(bias + 4*lane);
  const int g = lane >> 3;
  const float NEG_INF = -__builtin_inff();

  const float4 l4 = *(const float4*)(lg + (size_t)t*NE + 4*lane);
  float4 r4;   // uncorrected sigmoid scores
  r4.x = 1.f/(1.f + expf(-l4.x));
  r4.y = 1.f/(1.f + expf(-l4.y));
  r4.z = 1.f/(1.f + expf(-l4.z));
  r4.w = 1.f/(1.f + expf(-l4.w));
  float4 s4;   // corrected
  s4.x = r4.x + bias4.x; s4.y = r4.y + bias4.y;
  s4.z = r4.z + bias4.z; s4.w = r4.w + bias4.w;

  float m1 = s4.x, m2 = NEG_INF;
  if (s4.y > m1) { m2 = m1; m1 = s4.y; } else if (s4.y > m2) m2 = s4.y;
  if (s4.z > m1) { m2 = m1; m1 = s4.z; } else if (s4.z > m2) m2 = s4.z;
  if (s4.w > m1) { m2 = m1; m1 = s4.w; } else if (s4.w > m2) m2 = s4.w;
#pragma unroll
  for (int m = 1; m <= 4; m <<= 1) {
    const float o1 = __shfl_xor(m1, m);
    const float o2 = __shfl_xor(m2, m);
    const float nm1 = fmaxf(m1, o1);
    const float nm2 = fmaxf(fminf(m1, o1), fmaxf(m2, o2));
    m1 = nm1; m2 = nm2;
  }
  const float gs = m1 + m2;

  float gsv[8];
#pragma unroll
  for (int j = 0; j < 8; ++j) gsv[j] = __shfl(gs, j * 8);

  unsigned gm = 0;
#pragma unroll
  for (int r = 0; r < TOPKG; ++r) {
    float best = NEG_INF; int bj = 0;
#pragma unroll
    for (int j = 0; j < 8; ++j) {
      const bool avail = !((gm >> j) & 1u);
      if (avail && gsv[j] > best) { best = gsv[j]; bj = j; }
    }
    gm |= 1u << bj;
  }
  const bool allowed = (gm >> g) & 1u;

  float v0 = allowed ? s4.x : 0.f;
  float v1 = allowed ? s4.y : 0.f;
  float v2 = allowed ? s4.z : 0.f;
  float v3 = allowed ? s4.w : 0.f;

  float sumw = 0.f;
  int myidx = 0; float myraw = 0.f;
#pragma unroll
  for (int r = 0; r < TOPK; ++r) {
    float bv = v0; int bj = 0;
    if (v1 > bv) { bv = v1; bj = 1; }
    if (v2 > bv) { bv = v2; bj = 2; }
    if (v3 > bv) { bv = v3; bj = 3; }
    int bidx = 4 * lane + bj;
#pragma unroll
    for (int m = 1; m < 64; m <<= 1) {
      const float ov = __shfl_xor(bv, m);
      const int   oi = __shfl_xor(bidx, m);
      if (ov > bv || (ov == bv && oi < bidx)) { bv = ov; bidx = oi; }
    }
    const int oj = bidx & 3;
    const float cand = (oj == 0) ? r4.x
                     : (oj == 1) ? r4.y
                     : (oj == 2) ? r4.z
                     :             r4.w;
    const float raw = __shfl(cand, bidx >> 2);
    sumw += raw;
    if (lane == r) { myidx = bidx; myraw = raw; }
    if (lane == (bidx >> 2)) {
      if      (oj == 0) v0 = NEG_INF;
      else if (oj == 1) v1 = NEG_INF;
      else if (oj == 2) v2 = NEG_INF;
      else              v3 = NEG_INF;
    }
  }

  if (lane < TOPK) {
    out[(size_t)t * TOPK + lane] = (float)myidx;
    out[(size_t)T * TOPK + (size_t)t * TOPK + lane] = myraw / (sumw + 1e-20f) * 2.5f;
  }
}

extern "C" void kernel_launch(void* const* d_in, const int* in_sizes, int n_in,
                              void* d_out, int out_size, void* d_ws, size_t ws_size,
                              hipStream_t stream) {
  const float* hs   = (const float*)d_in[0];
  const float* wgt  = (const float*)d_in[1];
  const float* bias = (const float*)d_in[2];
  float* out = (float*)d_out;

  const int T = in_sizes[0] / HH;   // 8192

  unsigned short* bh = (unsigned short*)d_ws;
  unsigned short* bm = bh + (size_t)NE*HH;
  float* lgbuf = (float*)(bm + (size_t)NE*HH);   // 8.4 MB; total ws use 15.7 MB

  hipLaunchKernelGGL(prep_w, dim3(896), dim3(256), 0, stream, wgt, bh, bm);
  hipLaunchKernelGGL(gemm,   dim3(256), dim3(512), 0, stream, hs, bh, bm, lgbuf);
  hipLaunchKernelGGL(gate,   dim3(T/4), dim3(256), 0, stream, lgbuf, bias, out, T);
}

// Round 8
// 459.927 us; speedup vs baseline: 1.2994x; 1.2994x over previous
//
#include <hip/hip_runtime.h>
#include <cmath>

typedef __attribute__((ext_vector_type(8))) _Float16 half8;
typedef __attribute__((ext_vector_type(8))) unsigned short ushort8;
typedef __attribute__((ext_vector_type(4))) float f32x4;

#define HH 7168
#define NE 256
#define NQ 224        // K32 chunks
#define NITER 112     // BK=64 iterations
#define TOPK 8
#define TOPKG 4
#define WSC 1024.f
#define INV_WS (1.f/1024.f)
#define C1 (1.f/2048.f)       // 2^-11
#define C2 (1.f/4194304.f)    // 2^-22

// 2-level f16 split: x = h + m*2^-11, residual ~2^-25|x|
__device__ __forceinline__ void split2(float x, unsigned short& h, unsigned short& m){
  const _Float16 hh = (_Float16)x;
  const float r = x - (float)hh;                 // exact
  const _Float16 mm = (_Float16)(r * 2048.f);
  h = __builtin_bit_cast(unsigned short, hh);
  m = __builtin_bit_cast(unsigned short, mm);
}

// W*1024 -> (h,m) f16 in MFMA B-fragment order, coalesced writes.
// slot(q,nt,L) holds B[k=32q+8(L>>4)+j][e=16nt+(L&15)], j=0..7.
__global__ __launch_bounds__(256) void prep_w(const float* __restrict__ wgt,
                                              unsigned short* __restrict__ bh,
                                              unsigned short* __restrict__ bm){
  const int b = blockIdx.x;                 // 896 = 16 nt * 56 q-groups
  const int nt = b & 15, qb = (b >> 4) * 4;
  const int w = threadIdx.x >> 6, L = threadIdx.x & 63;
  const int q = qb + w;
  const int e = nt*16 + (L & 15);
  const int k0 = 32*q + 8*(L >> 4);
  const float4 a0 = *(const float4*)(wgt + (size_t)e*HH + k0);
  const float4 a1 = *(const float4*)(wgt + (size_t)e*HH + k0 + 4);
  const float v[8] = {a0.x,a0.y,a0.z,a0.w,a1.x,a1.y,a1.z,a1.w};
  ushort8 h8, m8;
#pragma unroll
  for(int j=0;j<8;j++){ unsigned short hh,mm; split2(v[j]*WSC, hh, mm); h8[j]=hh; m8[j]=mm; }
  const size_t base = ((size_t)(q*16+nt)*64 + L)*8;
  *(ushort8*)(bh+base) = h8;
  *(ushort8*)(bm+base) = m8;
}

// ---------------- GEMM: R2 (209us, proven) + wave-role phase stagger ----------------
// Block = 32 tok x 128 exp (slice), 512 thr / 8 waves (2mtp x 4ntp), BK=64,
// grid 512 -> 2 blocks/CU (16 waves/CU). B staged via global_load_lds dbuf;
// A staged by threads 0-255 (split2 + swizzled ds_write, 0-conflict proven).
// R8 delta (only change vs R2): staging waves run stage -> compute, non-staging
// waves run compute immediately; ga pipeline shifted one iter earlier so the
// early stage has zero vmem wait (full-drain barrier retired it last iter).
// Breaks the per-iter phase lockstep: half the waves do split2-VALU/ds_write
// while the other half do ds_read/MFMA -> DS-read queue storm halves.
// Per-wave arithmetic order identical to R2 -> bit-identical logits, absmax 0.
#define AB(buf,lvl,mt,q,row) ((((((buf)*2+(lvl))*2+(mt))*2+(q))*64+(row))*16)
#define BB(buf,lvl,q,nt) ((((buf)*4+(lvl)*2+(q))*8+(nt))<<10)
__device__ __forceinline__ int swz(int bo){ return bo ^ (((bo >> 8) & 7) << 4); }

__device__ __forceinline__ void glds16(const void* g, void* l){
  __builtin_amdgcn_global_load_lds(
      (const __attribute__((address_space(1))) unsigned int*)g,
      (__attribute__((address_space(3))) unsigned int*)l, 16, 0, 0);
}

__global__ __launch_bounds__(512,4)
void gemm(const float* __restrict__ hs,
          const unsigned short* __restrict__ bhp,
          const unsigned short* __restrict__ bmp,
          float* __restrict__ lgout){
  __shared__ __align__(16) unsigned char blds[65536];  // 2buf x 2lvl x 2q x 8nt x 1KB
  __shared__ __align__(16) unsigned char alds[16384];  // 2buf x 2lvl x 2mt x 2q x 64row x 16B

  const int tid = threadIdx.x, lane = tid & 63, w = tid >> 6;
  const int b = blockIdx.x;
  const int slice = (b >> 2) & 1;          // XCD 0-3 -> slice0, 4-7 -> slice1 (L2-resident)
  const int tg = (b >> 3)*4 + (b & 3);     // 0..255
  const int tb = tg*32, eb = slice*128;
  const int mtp = w >> 2, ntp = w & 3;

  f32x4 ksum[2], kcmp[2], c0[2], c1[2], c2[2];
#pragma unroll
  for(int cc=0;cc<2;cc++){ ksum[cc]=f32x4{0,0,0,0}; kcmp[cc]=f32x4{0,0,0,0}; }

  // A staging ids (threads 0..255 only)
  const int tokS = (tid & 255) >> 3, kidx = tid & 7;
  const int mtS = tokS >> 4, m16S = tokS & 15;
  const int qS = kidx >> 2, kgS = kidx & 3;
  const int rowS = kgS*16 + m16S;
  const float* agp = hs + (size_t)(tb + tokS)*HH + kidx*8;
  float4 ga[2];

  auto stage = [&](int buf){
    unsigned short h[8], m[8];
    const float* gv = (const float*)ga;
#pragma unroll
    for(int p=0;p<8;p++) split2(gv[p], h[p], m[p]);
    ushort8 h8, m8;
#pragma unroll
    for(int j=0;j<8;j++){ h8[j]=h[j]; m8[j]=m[j]; }
    *(ushort8*)&alds[swz(AB(buf,0,mtS,qS,rowS))] = h8;
    *(ushort8*)&alds[swz(AB(buf,1,mtS,qS,rowS))] = m8;
  };

  // B staging: 32 slots (2lvl x 2q x 8nt) of 1KB per buf, 4 glds16 per wave
  auto bstage = [&](int buf, int inext){
#pragma unroll
    for(int j=0;j<4;j++){
      const int sid = w*4 + j;
      const int lvl = sid >> 4, q = (sid >> 3) & 1, nt = sid & 7;
      const int q32 = 2*inext + q;
      const unsigned short* src = (lvl ? bmp : bhp)
          + ((size_t)((q32*16 + slice*8 + nt)*64 + lane))*8;
      glds16(src, &blds[BB(buf,lvl,q,nt)]);
    }
  };

  auto compute = [&](int cur, int s){
    const half8 ah = *(const half8*)&alds[swz(AB(cur,0,mtp,s,lane))];
    const half8 am = *(const half8*)&alds[swz(AB(cur,1,mtp,s,lane))];
    half8 Bh[2], Bm[2];
#pragma unroll
    for(int ntl=0;ntl<2;ntl++){
      Bh[ntl] = *(const half8*)&blds[BB(cur,0,s,ntp*2+ntl) + lane*16];
      Bm[ntl] = *(const half8*)&blds[BB(cur,1,s,ntp*2+ntl) + lane*16];
    }
    __builtin_amdgcn_s_setprio(1);
#pragma unroll
    for(int ntl=0;ntl<2;ntl++){
      c0[ntl] = __builtin_amdgcn_mfma_f32_16x16x32_f16(ah, Bh[ntl], c0[ntl], 0,0,0);
      c1[ntl] = __builtin_amdgcn_mfma_f32_16x16x32_f16(ah, Bm[ntl], c1[ntl], 0,0,0);
      c1[ntl] = __builtin_amdgcn_mfma_f32_16x16x32_f16(am, Bh[ntl], c1[ntl], 0,0,0);
      c2[ntl] = __builtin_amdgcn_mfma_f32_16x16x32_f16(am, Bm[ntl], c2[ntl], 0,0,0);
    }
    __builtin_amdgcn_s_setprio(0);
  };

  // ---- prologue: A chunk 0 staged; ga pre-loaded with chunk 1; B chunk 0 in flight
  if(tid < 256){
    ga[0] = *(const float4*)(agp);
    ga[1] = *(const float4*)(agp + 4);
  }
  bstage(0, 0);
  if(tid < 256){
    stage(0);
    ga[0] = *(const float4*)(agp + 64);
    ga[1] = *(const float4*)(agp + 68);
  }
  __syncthreads();

#pragma unroll 1
  for(int i=0;i<NITER;i++){
    const int cur = i & 1, nb = cur ^ 1;
    const bool more = (i+1 < NITER);
    if(more) bstage(nb, i+1);
    if((i & 1) == 0){
#pragma unroll
      for(int cc=0;cc<2;cc++){ c0[cc]=f32x4{0,0,0,0}; c1[cc]=f32x4{0,0,0,0}; c2[cc]=f32x4{0,0,0,0}; }
    }
    // staggered roles: staging waves stage FIRST (ga already resident -- loaded
    // last iter, retired by the full-drain barrier), then reload ga for i+2;
    // non-staging waves go straight to ds_read/MFMA.
    if(tid < 256){
      if(more) stage(nb);
      if(i <= NITER-3){
        const float* ap = agp + (size_t)(i+2)*64;
        ga[0] = *(const float4*)(ap);
        ga[1] = *(const float4*)(ap + 4);
      }
    }
    compute(cur, 0);
    compute(cur, 1);
    if(i & 1){
      // Kahan flush of the completed 128-K window (same points as R2 -> bit-identical)
#pragma unroll
      for(int cc=0;cc<2;cc++)
#pragma unroll
        for(int r=0;r<4;r++){
          const float v = c0[cc][r] + c1[cc][r]*C1 + c2[cc][r]*C2;
          const float y = v - kcmp[cc][r];
          const float t = ksum[cc][r] + y;
          kcmp[cc][r] = (t - ksum[cc][r]) - y;
          ksum[cc][r] = t;
        }
    }
    __syncthreads();
  }

  // epilogue: C layout col=lane&15 (expert), row=(lane>>4)*4+r (token); undo W scale
#pragma unroll
  for(int ntl=0;ntl<2;ntl++)
#pragma unroll
    for(int r=0;r<4;r++){
      const int tok = mtp*16 + (lane>>4)*4 + r;
      const int e = (ntp*2+ntl)*16 + (lane&15);
      const float lg = (ksum[ntl][r] - kcmp[ntl][r]) * INV_WS;
      lgout[(size_t)(tb+tok)*NE + eb + e] = lg;
    }
}

// Gating, 1 token per wave, grid T/4.
__global__ __launch_bounds__(256)
void gate(const float* __restrict__ lg, const float* __restrict__ bias,
          float* __restrict__ out, int T){
  const int tid = threadIdx.x, lane = tid & 63, wv = tid >> 6;
  const int t = blockIdx.x*4 + wv;
  const float4 bias4 = *(const float4*)(bias + 4*lane);
  const int g = lane >> 3;
  const float NEG_INF = -__builtin_inff();

  const float4 l4 = *(const float4*)(lg + (size_t)t*NE + 4*lane);
  float4 r4;   // uncorrected sigmoid scores
  r4.x = 1.f/(1.f + expf(-l4.x));
  r4.y = 1.f/(1.f + expf(-l4.y));
  r4.z = 1.f/(1.f + expf(-l4.z));
  r4.w = 1.f/(1.f + expf(-l4.w));
  float4 s4;   // corrected
  s4.x = r4.x + bias4.x; s4.y = r4.y + bias4.y;
  s4.z = r4.z + bias4.z; s4.w = r4.w + bias4.w;

  float m1 = s4.x, m2 = NEG_INF;
  if (s4.y > m1) { m2 = m1; m1 = s4.y; } else if (s4.y > m2) m2 = s4.y;
  if (s4.z > m1) { m2 = m1; m1 = s4.z; } else if (s4.z > m2) m2 = s4.z;
  if (s4.w > m1) { m2 = m1; m1 = s4.w; } else if (s4.w > m2) m2 = s4.w;
#pragma unroll
  for (int m = 1; m <= 4; m <<= 1) {
    const float o1 = __shfl_xor(m1, m);
    const float o2 = __shfl_xor(m2, m);
    const float nm1 = fmaxf(m1, o1);
    const float nm2 = fmaxf(fminf(m1, o1), fmaxf(m2, o2));
    m1 = nm1; m2 = nm2;
  }
  const float gs = m1 + m2;

  float gsv[8];
#pragma unroll
  for (int j = 0; j < 8; ++j) gsv[j] = __shfl(gs, j * 8);

  unsigned gm = 0;
#pragma unroll
  for (int r = 0; r < TOPKG; ++r) {
    float best = NEG_INF; int bj = 0;
#pragma unroll
    for (int j = 0; j < 8; ++j) {
      const bool avail = !((gm >> j) & 1u);
      if (avail && gsv[j] > best) { best = gsv[j]; bj = j; }
    }
    gm |= 1u << bj;
  }
  const bool allowed = (gm >> g) & 1u;

  float v0 = allowed ? s4.x : 0.f;
  float v1 = allowed ? s4.y : 0.f;
  float v2 = allowed ? s4.z : 0.f;
  float v3 = allowed ? s4.w : 0.f;

  float sumw = 0.f;
  int myidx = 0; float myraw = 0.f;
#pragma unroll
  for (int r = 0; r < TOPK; ++r) {
    float bv = v0; int bj = 0;
    if (v1 > bv) { bv = v1; bj = 1; }
    if (v2 > bv) { bv = v2; bj = 2; }
    if (v3 > bv) { bv = v3; bj = 3; }
    int bidx = 4 * lane + bj;
#pragma unroll
    for (int m = 1; m < 64; m <<= 1) {
      const float ov = __shfl_xor(bv, m);
      const int   oi = __shfl_xor(bidx, m);
      if (ov > bv || (ov == bv && oi < bidx)) { bv = ov; bidx = oi; }
    }
    const int oj = bidx & 3;
    const float cand = (oj == 0) ? r4.x
                     : (oj == 1) ? r4.y
                     : (oj == 2) ? r4.z
                     :             r4.w;
    const float raw = __shfl(cand, bidx >> 2);
    sumw += raw;
    if (lane == r) { myidx = bidx; myraw = raw; }
    if (lane == (bidx >> 2)) {
      if      (oj == 0) v0 = NEG_INF;
      else if (oj == 1) v1 = NEG_INF;
      else if (oj == 2) v2 = NEG_INF;
      else              v3 = NEG_INF;
    }
  }

  if (lane < TOPK) {
    out[(size_t)t * TOPK + lane] = (float)myidx;
    out[(size_t)T * TOPK + (size_t)t * TOPK + lane] = myraw / (sumw + 1e-20f) * 2.5f;
  }
}

extern "C" void kernel_launch(void* const* d_in, const int* in_sizes, int n_in,
                              void* d_out, int out_size, void* d_ws, size_t ws_size,
                              hipStream_t stream) {
  const float* hs   = (const float*)d_in[0];
  const float* wgt  = (const float*)d_in[1];
  const float* bias = (const float*)d_in[2];
  float* out = (float*)d_out;

  const int T = in_sizes[0] / HH;   // 8192

  unsigned short* bh = (unsigned short*)d_ws;
  unsigned short* bm = bh + (size_t)NE*HH;
  float* lgbuf = (float*)(bm + (size_t)NE*HH);   // 8.4 MB; total ws use 15.7 MB

  hipLaunchKernelGGL(prep_w, dim3(896), dim3(256), 0, stream, wgt, bh, bm);
  hipLaunchKernelGGL(gemm,   dim3(512), dim3(512), 0, stream, hs, bh, bm, lgbuf);
  hipLaunchKernelGGL(gate,   dim3(T/4), dim3(256), 0, stream, lgbuf, bias, out, T);
}